// Round 3
// baseline (1364.842 us; speedup 1.0000x reference)
//
#include <hip/hip_runtime.h>
#include <hip/hip_cooperative_groups.h>
#include <math.h>

namespace cg = cooperative_groups;

typedef float nfloat4 __attribute__((ext_vector_type(4)));  // native vec for nontemporal builtin

// x is (256, 512, 1024) fp32 = 512 MiB
constexpr int ROWS    = 256;
constexpr int ROWLEN  = 512 * 1024;            // elements per row
constexpr int BLOCK   = 256;                   // 4 waves
constexpr int GRID    = 1024;                  // 4 blocks/CU co-resident (cooperative)
constexpr int BPR     = GRID / ROWS;           // 4 blocks per row
constexpr int ROWF4   = ROWLEN / 4;            // 131072 float4 per row
constexpr int CHUNKF4 = ROWF4 / BPR;           // 32768 float4 per block
constexpr int FPT     = CHUNKF4 / BLOCK;       // 128 float4 per thread

// __launch_bounds__(256, 4): 4 waves/EU => VGPR<=128 => >=4 blocks/CU,
// guaranteeing co-residency of all 1024 blocks for the cooperative launch.
__global__ __launch_bounds__(BLOCK, 4) void fused_quant_relu(
    const float4* __restrict__ x, float4* __restrict__ out,
    float* __restrict__ pmin, float* __restrict__ pmax) {
  const int bid = blockIdx.x;
  const int row = bid / BPR;
  const int sub = bid % BPR;
  const int tid = threadIdx.x;
  const float4* p = x + (size_t)row * ROWF4 + (size_t)sub * CHUNKF4;

  // ---- Pass A: per-block min/max over own 512 KiB chunk (ascending walk) ----
  float vmin = INFINITY, vmax = -INFINITY;
#pragma unroll 8
  for (int i = 0; i < FPT; ++i) {
    float4 v = p[tid + i * BLOCK];             // coalesced 16 B/lane
    vmin = fminf(vmin, fminf(fminf(v.x, v.y), fminf(v.z, v.w)));
    vmax = fmaxf(vmax, fmaxf(fmaxf(v.x, v.y), fmaxf(v.z, v.w)));
  }
  // wave64 butterfly
#pragma unroll
  for (int off = 32; off > 0; off >>= 1) {
    vmin = fminf(vmin, __shfl_xor(vmin, off, 64));
    vmax = fmaxf(vmax, __shfl_xor(vmax, off, 64));
  }
  __shared__ float smin[BLOCK / 64], smax[BLOCK / 64];
  const int wave = tid >> 6, lane = tid & 63;
  if (lane == 0) { smin[wave] = vmin; smax[wave] = vmax; }
  __syncthreads();
  if (tid == 0) {
    float a = fminf(fminf(smin[0], smin[1]), fminf(smin[2], smin[3]));
    float b = fmaxf(fmaxf(smax[0], smax[1]), fmaxf(smax[2], smax[3]));
    // agent-scope release: per-XCD L2s are not coherent (G16)
    __hip_atomic_store(&pmin[bid], a, __ATOMIC_RELEASE, __HIP_MEMORY_SCOPE_AGENT);
    __hip_atomic_store(&pmax[bid], b, __ATOMIC_RELEASE, __HIP_MEMORY_SCOPE_AGENT);
  }

  cg::this_grid().sync();

  // ---- Fold this row's partials (agent-scope acquire) ----
  float m = INFINITY, M = -INFINITY;
#pragma unroll
  for (int i = 0; i < BPR; ++i) {
    m = fminf(m, __hip_atomic_load(&pmin[row * BPR + i], __ATOMIC_ACQUIRE, __HIP_MEMORY_SCOPE_AGENT));
    M = fmaxf(M, __hip_atomic_load(&pmax[row * BPR + i], __ATOMIC_ACQUIRE, __HIP_MEMORY_SCOPE_AGENT));
  }
  const float rng   = M - m;
  const float scale = 254.0f / rng;            // quant scale
  const float step  = rng / 254.0f;            // dequant step

  // ---- Pass B: re-read own chunk TAIL-FIRST (tail is the L3-resident part
  // after pass A's ascending stream), quantize, nontemporal store (out is
  // never re-read — keep it out of L3 so it doesn't evict x residue). ----
  nfloat4* q = (nfloat4*)(out + (size_t)row * ROWF4 + (size_t)sub * CHUNKF4);
#pragma unroll 4
  for (int i = FPT - 1; i >= 0; --i) {
    const int idx = tid + i * BLOCK;
    float4 v = p[idx];
    nfloat4 o;
    // r = round_half_even(254*(x-m)/rng - 127); out = relu((r+127)*rng/254 + m)
    o.x = fmaxf(fmaf(rintf(fmaf(v.x - m, scale, -127.0f)) + 127.0f, step, m), 0.0f);
    o.y = fmaxf(fmaf(rintf(fmaf(v.y - m, scale, -127.0f)) + 127.0f, step, m), 0.0f);
    o.z = fmaxf(fmaf(rintf(fmaf(v.z - m, scale, -127.0f)) + 127.0f, step, m), 0.0f);
    o.w = fmaxf(fmaf(rintf(fmaf(v.w - m, scale, -127.0f)) + 127.0f, step, m), 0.0f);
    __builtin_nontemporal_store(o, &q[idx]);
  }
}

extern "C" void kernel_launch(void* const* d_in, const int* in_sizes, int n_in,
                              void* d_out, int out_size, void* d_ws, size_t ws_size,
                              hipStream_t stream) {
  const float4* x    = (const float4*)d_in[0];
  float4*       out  = (float4*)d_out;
  float*        pmin = (float*)d_ws;           // GRID floats
  float*        pmax = pmin + GRID;            // GRID floats (8 KiB total)

  void* args[] = {(void*)&x, (void*)&out, (void*)&pmin, (void*)&pmax};
  (void)hipLaunchCooperativeKernel((void*)fused_quant_relu, dim3(GRID), dim3(BLOCK),
                                   args, 0, stream);
}